// Round 2
// baseline (251.783 us; speedup 1.0000x reference)
//
#include <hip/hip_runtime.h>

// PositionalEncoding: out[b,s,i] = x[b,s,i] + pe[s,i]
//   pe[s,i] = sin(s / 10000^((i/2)/D)) if i even, cos(...) if i odd
// B=8, S=4096, D=1024, fp32. Memory-bound: ~200 MB HBM traffic (reads half
// L3-resident) -> ~35-45 us floor.
//
// R1 lesson: VGPR=28 meant the compiler serialized the b-loop (1 outstanding
// load/lane -> 8 sequential HBM round trips -> 2.2 TB/s). R2: hoist all 8
// loads into registers first (8 outstanding vmem/lane), compute PE while
// they're in flight, then add+store with nontemporal stores (don't evict x
// from L2/L3).

#define PE_B 8
#define PE_S 4096
#define PE_D 1024

typedef float v4f __attribute__((ext_vector_type(4)));

__global__ __launch_bounds__(256) void pe_add_kernel(
    const float* __restrict__ x, float* __restrict__ out) {
    const int tid = blockIdx.x * blockDim.x + threadIdx.x;   // 0 .. S*D/4-1
    const int i   = (tid & (PE_D / 4 - 1)) * 4;              // elem index in row
    const int s   = tid >> 8;                                // D/4 = 256

    const size_t off    = (size_t)tid * 4;
    const size_t stride = (size_t)PE_S * PE_D;

    // Issue all 8 batch loads up front -> 8 outstanding global_load_dwordx4
    // per lane. No use until the add loop below.
    v4f v[PE_B];
#pragma unroll
    for (int b = 0; b < PE_B; ++b)
        v[b] = *(const v4f*)(x + b * stride + off);

    // PE computed while the loads are in flight (independent of them).
    const float pos = (float)s;
    const float c   = -13.287712379549449f / (float)PE_D;   // -log2(10000)/D
    const float k0  = (float)(i >> 1);
    const float a0  = pos * exp2f(k0 * c);
    const float a1  = pos * exp2f((k0 + 1.0f) * c);
    float s0, c0, s1, c1;
    sincosf(a0, &s0, &c0);
    sincosf(a1, &s1, &c1);
    // lanes i (even)->sin(a0), i+1->cos(a0), i+2->sin(a1), i+3->cos(a1)
    const v4f pe = {s0, c0, s1, c1};

#pragma unroll
    for (int b = 0; b < PE_B; ++b) {
        const v4f r = v[b] + pe;
        // Streaming store: out is write-once, keep it out of L2/L3 so x's
        // L3 residency (the FETCH-halving effect) survives.
        __builtin_nontemporal_store(r, (v4f*)(out + b * stride + off));
    }
}

extern "C" void kernel_launch(void* const* d_in, const int* in_sizes, int n_in,
                              void* d_out, int out_size, void* d_ws, size_t ws_size,
                              hipStream_t stream) {
    const float* x = (const float*)d_in[0];
    float* out = (float*)d_out;
    const int threads = PE_S * PE_D / 4;   // 1,048,576 -> 4096 blocks of 256
    pe_add_kernel<<<threads / 256, 256, 0, stream>>>(x, out);
}

// Round 3
// 228.218 us; speedup vs baseline: 1.1033x; 1.1033x over previous
//
#include <hip/hip_runtime.h>

// PositionalEncoding: out[b,s,i] = x[b,s,i] + pe[s,i]
//   pe[s,i] = sin(s / 10000^((i/2)/D)) if i even, cos(...) if i odd
// B=8, S=4096, D=1024, fp32.
//
// R1/R2 lesson: batch-amortizing PE forced each thread onto 16 streams at
// 16MB stride -> TLB/page thrash, ~2 TB/s (4 B/cyc/CU vs 10 at copy peak),
// and the compiler refused to hoist the 8 loads (VGPR stayed 28). R3:
// copy-shaped kernel. Kernel 1 materializes the 16MB pe table in d_ws
// (transcendentals once per (s,i), ~3 us). Kernel 2 is a pure contiguous
// 3-stream add: x (HBM/L3), pe (16MB, L2/L3-hot), out. One float4/thread,
// full occupancy, maximal page sharing between neighboring waves.

#define PE_B 8
#define PE_S 4096
#define PE_D 1024
#define ROW4 (PE_S * PE_D / 4)          // float4s per batch = 1,048,576

typedef float v4f __attribute__((ext_vector_type(4)));

__global__ __launch_bounds__(256) void pe_table_kernel(v4f* __restrict__ pe_tab) {
    const int tid = blockIdx.x * blockDim.x + threadIdx.x;   // 0 .. ROW4-1
    const int i   = (tid & (PE_D / 4 - 1)) * 4;              // elem index in row
    const int s   = tid >> 8;                                // D/4 = 256

    const float pos = (float)s;
    const float c   = -13.287712379549449f / (float)PE_D;   // -log2(10000)/D
    const float k0  = (float)(i >> 1);
    const float a0  = pos * exp2f(k0 * c);
    const float a1  = pos * exp2f((k0 + 1.0f) * c);
    float s0, c0, s1, c1;
    sincosf(a0, &s0, &c0);
    sincosf(a1, &s1, &c1);
    const v4f pe = {s0, c0, s1, c1};     // even->sin, odd->cos
    pe_tab[tid] = pe;
}

__global__ __launch_bounds__(256) void pe_add_kernel(
    const float* __restrict__ x, const v4f* __restrict__ pe_tab,
    float* __restrict__ out) {
    const int idx = blockIdx.x * blockDim.x + threadIdx.x;   // 0 .. B*ROW4-1
    const v4f v = *(const v4f*)(x + (size_t)idx * 4);
    const v4f p = pe_tab[idx & (ROW4 - 1)];
    *(v4f*)(out + (size_t)idx * 4) = v + p;
}

// Fallback if ws is too small: fused recompute per element (contiguous too).
__global__ __launch_bounds__(256) void pe_fused_kernel(
    const float* __restrict__ x, float* __restrict__ out) {
    const int idx = blockIdx.x * blockDim.x + threadIdx.x;
    const int r   = idx & (ROW4 - 1);
    const int i   = (r & (PE_D / 4 - 1)) * 4;
    const int s   = r >> 8;

    const v4f v = *(const v4f*)(x + (size_t)idx * 4);

    const float pos = (float)s;
    const float c   = -13.287712379549449f / (float)PE_D;
    const float k0  = (float)(i >> 1);
    const float a0  = pos * exp2f(k0 * c);
    const float a1  = pos * exp2f((k0 + 1.0f) * c);
    float s0, c0, s1, c1;
    sincosf(a0, &s0, &c0);
    sincosf(a1, &s1, &c1);
    const v4f pe = {s0, c0, s1, c1};
    *(v4f*)(out + (size_t)idx * 4) = v + pe;
}

extern "C" void kernel_launch(void* const* d_in, const int* in_sizes, int n_in,
                              void* d_out, int out_size, void* d_ws, size_t ws_size,
                              hipStream_t stream) {
    const float* x = (const float*)d_in[0];
    float* out = (float*)d_out;
    const int n4 = PE_B * ROW4;                       // 8,388,608 float4s

    if (ws_size >= (size_t)PE_S * PE_D * sizeof(float)) {
        v4f* pe_tab = (v4f*)d_ws;
        pe_table_kernel<<<ROW4 / 256, 256, 0, stream>>>(pe_tab);
        pe_add_kernel<<<n4 / 256, 256, 0, stream>>>(x, pe_tab, out);
    } else {
        pe_fused_kernel<<<n4 / 256, 256, 0, stream>>>(x, out);
    }
}